// Round 15
// baseline (1014.020 us; speedup 1.0000x reference)
//
#include <hip/hip_runtime.h>
#include <math.h>

#define BB 32
#define TT 128
#define EE 128
#define HD 128
#define G4 512   // 4*H
#define NV 32000

typedef _Float16 f16x2  __attribute__((ext_vector_type(2)));
typedef _Float16 f16x4v __attribute__((ext_vector_type(4)));
typedef _Float16 f16x8  __attribute__((ext_vector_type(8)));
typedef float    f32x4  __attribute__((ext_vector_type(4)));

// ---------------- Kernel A (fused): blocks 0..1999 split Wd, 2000..2511 embed ----------------
__global__ __launch_bounds__(256) void k_prep(
    const int* __restrict__ inputs, const float* __restrict__ emb,
    const float* __restrict__ W0, const float* __restrict__ b0,
    float* __restrict__ Z0x,
    const float* __restrict__ Wd, _Float16* __restrict__ Whi, _Float16* __restrict__ Wlo)
{
    if (blockIdx.x < 2000) {
        if (Whi == nullptr) return;   // small-ws fallback: no split buffers
        const int g = blockIdx.x * 256 + threadIdx.x;
        const int chunk = g >> 6;           // 0..7999
        const int lane = g & 63;
        const int ntile = chunk >> 2;
        const int kstep = chunk & 3;
        const int n = ntile * 16 + (lane & 15);
        const int kb = kstep * 32 + (lane >> 4) * 8;
        _Float16 hi[8], lo[8];
        #pragma unroll
        for (int j = 0; j < 8; ++j) {
            float v = Wd[(size_t)(kb + j) * NV + n];
            hi[j] = (_Float16)v;
            lo[j] = (_Float16)(v - (float)hi[j]);
        }
        *(float4*)&Whi[(size_t)chunk * 512 + lane * 8] = *(const float4*)hi;
        *(float4*)&Wlo[(size_t)chunk * 512 + lane * 8] = *(const float4*)lo;
        return;
    }
    __shared__ float xs[8][EE];
    const int r0 = (blockIdx.x - 2000) * 8;
    const int tid = threadIdx.x;
    for (int i = tid; i < 8 * EE; i += 256) {
        int r = i >> 7, e = i & 127;
        int tok = inputs[r0 + r];
        xs[r][e] = emb[tok * EE + e];
    }
    __syncthreads();
    const int c2 = tid * 2;
    float2 bb2 = *(const float2*)&b0[c2];
    float acc[8][2];
    #pragma unroll
    for (int r = 0; r < 8; ++r) { acc[r][0] = bb2.x; acc[r][1] = bb2.y; }
    for (int e = 0; e < EE; ++e) {
        float2 w = *(const float2*)&W0[e * G4 + c2];
        #pragma unroll
        for (int r = 0; r < 8; ++r) {
            float x = xs[r][e];
            acc[r][0] = fmaf(x, w.x, acc[r][0]);
            acc[r][1] = fmaf(x, w.y, acc[r][1]);
        }
    }
    #pragma unroll
    for (int r = 0; r < 8; ++r) {
        float2 o2; o2.x = acc[r][0]; o2.y = acc[r][1];
        *(float2*)&Z0x[(size_t)(r0 + r) * G4 + c2] = o2;
    }
}

// ---------------- Kernel B: 2-layer LSTM via MFMA, in-register gates, LDS-staged x/y ----------------
// 4 blocks x 256 thr. Wave w owns units [w*32, w*32+32) of all 4 gates
// (acc n = 2*gate + half). In-register gates (R14-verified layout). Fixes vs
// R14: x staged through LDS with coalesced loads issued early / ds_write late
// (T14), y staged through LDS and flushed coalesced next step, h row stride
// 152 f16 (bank-conflict-free fragment reads).
__device__ __forceinline__ float sigf(float x) {
    return __builtin_amdgcn_rcpf(1.f + __builtin_amdgcn_exp2f(x * -1.44269504088896f));
}
__device__ __forceinline__ float tanh_f(float x) {
    return 1.f - 2.f * __builtin_amdgcn_rcpf(1.f + __builtin_amdgcn_exp2f(x * 2.88539008177793f));
}
__device__ __forceinline__ f16x8 ldfrag(const float* __restrict__ M, int col, int k0) {
    f16x8 v;
    #pragma unroll
    for (int j = 0; j < 8; ++j) v[j] = (_Float16)M[(size_t)(k0 + j) * G4 + col];
    return v;
}

#define REP8(X) X(0) X(1) X(2) X(3) X(4) X(5) X(6) X(7)
#define MFMA(acc, a, b) acc = __builtin_amdgcn_mfma_f32_16x16x32_f16(a, b, acc, 0, 0, 0)
#define TSTR (TT * G4)
#define HR 152   // h row stride (f16): 304B -> (12*l)%32 banks, conflict-free
#define XR 516   // x row stride (f32)
#define YR 132   // y staging row stride (f32)

#define DECLF(n) f16x8 u0_##n##_0, u0_##n##_1, u0_##n##_2, u0_##n##_3, \
                       w1_##n##_0, w1_##n##_1, w1_##n##_2, w1_##n##_3, \
                       u1_##n##_0, u1_##n##_1, u1_##n##_2, u1_##n##_3; \
                 f32x4 aU1_##n, aZ_##n; float b1c_##n; int col_##n;

// gate-permuted column: n = 2*gate + half
#define LOADF(n) { col_##n = ((n) >> 1) * 128 + wu + ((n) & 1) * 16 + lo16; \
    const int cn = col_##n; \
    u0_##n##_0 = ldfrag(U0, cn, khi);      u0_##n##_1 = ldfrag(U0, cn, 32 + khi); \
    u0_##n##_2 = ldfrag(U0, cn, 64 + khi); u0_##n##_3 = ldfrag(U0, cn, 96 + khi); \
    w1_##n##_0 = ldfrag(W1, cn, khi);      w1_##n##_1 = ldfrag(W1, cn, 32 + khi); \
    w1_##n##_2 = ldfrag(W1, cn, 64 + khi); w1_##n##_3 = ldfrag(W1, cn, 96 + khi); \
    asm("" : "+a"(w1_##n##_0), "+a"(w1_##n##_1), "+a"(w1_##n##_2), "+a"(w1_##n##_3)); \
    u1_##n##_0 = ldfrag(U1, cn, khi);      u1_##n##_1 = ldfrag(U1, cn, 32 + khi); \
    u1_##n##_2 = ldfrag(U1, cn, 64 + khi); u1_##n##_3 = ldfrag(U1, cn, 96 + khi); \
    asm("" : "+a"(u1_##n##_0), "+a"(u1_##n##_1), "+a"(u1_##n##_2), "+a"(u1_##n##_3)); \
    b1c_##n = b1[cn]; }

#define PU1(n) { f32x4 a = {0.f, 0.f, 0.f, 0.f}; \
    MFMA(a, hb0, u1_##n##_0); MFMA(a, hb1, u1_##n##_1); \
    MFMA(a, hb2, u1_##n##_2); MFMA(a, hb3, u1_##n##_3); aU1_##n = a; }

// C-init from LDS-staged x (lanes>=32 are padding rows -> 0)
#define INITX(n) { if (lane < 32) { const float* xp = &xcurp[bq4][0] + col_##n; \
        aZ_##n[0] = xp[0]; aZ_##n[1] = xp[XR]; aZ_##n[2] = xp[2 * XR]; aZ_##n[3] = xp[3 * XR]; \
    } else { aZ_##n[0] = 0.f; aZ_##n[1] = 0.f; aZ_##n[2] = 0.f; aZ_##n[3] = 0.f; } }

#define PU0(n) { \
    MFMA(aZ_##n, ha0, u0_##n##_0); MFMA(aZ_##n, ha1, u0_##n##_1); \
    MFMA(aZ_##n, ha2, u0_##n##_2); MFMA(aZ_##n, ha3, u0_##n##_3); }

#define PW1(n) { f32x4 a = {b1c_##n, b1c_##n, b1c_##n, b1c_##n}; \
    MFMA(a, ha0, w1_##n##_0); MFMA(a, ha1, w1_##n##_1); \
    MFMA(a, ha2, w1_##n##_2); MFMA(a, ha3, w1_##n##_3); \
    aZ_##n = a + aU1_##n; }

// gates: acc n=2g+h -> zi:aZ_h, zf:aZ_{2+h}, zc:aZ_{4+h}, zo:aZ_{6+h}
#define G0R(nI, nF, nC, nO, CS, h, r) { \
    float ig = sigf(aZ_##nI[r]), fg = sigf(aZ_##nF[r]), og = sigf(aZ_##nO[r]); \
    float gg = tanh_f(aZ_##nC[r]); \
    float cn = fg * CS[r] + ig * gg; CS[r] = cn; \
    h0c[bq4 + r][wu + lo16 + 16 * (h)] = (_Float16)(og * tanh_f(cn)); }

#define G1R(nI, nF, nC, nO, CS, h, r) { \
    float ig = sigf(aZ_##nI[r]), fg = sigf(aZ_##nF[r]), og = sigf(aZ_##nO[r]); \
    float gg = tanh_f(aZ_##nC[r]); \
    float cn = fg * CS[r] + ig * gg; CS[r] = cn; float hn = og * tanh_f(cn); \
    h1c[bq4 + r][wu + lo16 + 16 * (h)] = (_Float16)hn; \
    yst[bq4 + r][wu + lo16 + 16 * (h)] = hn; }

__global__ __launch_bounds__(256, 1) void k_lstm_m3(
    const float* __restrict__ Z0x,
    const float* __restrict__ U0, const float* __restrict__ W1,
    const float* __restrict__ U1, const float* __restrict__ b1,
    float* __restrict__ y)
{
    const int tid  = threadIdx.x;
    const int lane = tid & 63;
    const int wu   = (tid >> 6) * 32;      // wave's unit base
    const int lo16 = lane & 15;
    const int khi  = (lane >> 4) * 8;
    const int B0   = blockIdx.x * 8;       // batch base
    const int bq4  = (lane >> 4) * 4;      // batch group (valid for lane<32)

    __shared__ _Float16 h0p[2][16][HR];    // double-buffered h, rows 8-15 stay 0
    __shared__ _Float16 h1p[2][16][HR];
    __shared__ float    xbf[2][8][XR];     // double-buffered x_t staging
    __shared__ float    yst[8][YR];        // y_t staging (single buffer)

    REP8(DECLF)
    REP8(LOADF)

    // cooperative x/y staging mapping: thread covers batch xbrow, 16 cols
    const int xbrow = tid >> 5;            // 0..7
    const int xcol0 = (tid & 31) * 16;     // 0..496
    const int ycol  = (tid & 31) * 4;      // 0..124
    const float* zxstage = Z0x + ((size_t)(B0 + xbrow) * TT) * G4 + xcol0;

    f32x4 c0a = {0.f,0.f,0.f,0.f}, c0b = {0.f,0.f,0.f,0.f};
    f32x4 c1a = {0.f,0.f,0.f,0.f}, c1b = {0.f,0.f,0.f,0.f};

    for (int i = tid; i < 2 * 16 * HR; i += 256) {
        (&h0p[0][0][0])[i] = (_Float16)0.f;
        (&h1p[0][0][0])[i] = (_Float16)0.f;
    }
    {   // stage x_0 into xbf[0]
        const float4* s = (const float4*)zxstage;
        float* xd = &xbf[0][xbrow][xcol0];
        ((float4*)xd)[0] = s[0]; ((float4*)xd)[1] = s[1];
        ((float4*)xd)[2] = s[2]; ((float4*)xd)[3] = s[3];
    }
    __syncthreads();

    for (int t = 0; t < TT; ++t) {
        const int p  = t & 1;
        const _Float16 (*h0r)[HR] = h0p[p ^ 1];
        const _Float16 (*h1r)[HR] = h1p[p ^ 1];
        _Float16 (*h0c)[HR] = h0p[p];
        _Float16 (*h1c)[HR] = h1p[p];
        const float (*xcurp)[XR] = xbf[p];

        // issue x_{t+1} loads EARLY (consumed by ds_write at end of phase A)
        const int tn = (t + 1 < TT) ? (t + 1) : (TT - 1);
        const float4* xs4 = (const float4*)(zxstage + (size_t)tn * G4);
        float4 px0 = xs4[0], px1 = xs4[1], px2 = xs4[2], px3 = xs4[3];

        // flush y_{t-1} (yst stable until gates-1 after the mid barrier)
        if (t > 0) {
            float4 yv = *(const float4*)&yst[xbrow][ycol];
            *(float4*)&y[((size_t)(B0 + xbrow) * TT + (t - 1)) * HD + ycol] = yv;
        }

        // ---- phase A: aU1 = U1^T h1_{t-1};  aZ = x_t + U0^T h0_{t-1} ----
        {
            f16x8 hb0 = *(const f16x8*)&h1r[lo16][khi];
            f16x8 hb1 = *(const f16x8*)&h1r[lo16][32 + khi];
            f16x8 hb2 = *(const f16x8*)&h1r[lo16][64 + khi];
            f16x8 hb3 = *(const f16x8*)&h1r[lo16][96 + khi];
            REP8(PU1)
            f16x8 ha0 = *(const f16x8*)&h0r[lo16][khi];
            f16x8 ha1 = *(const f16x8*)&h0r[lo16][32 + khi];
            f16x8 ha2 = *(const f16x8*)&h0r[lo16][64 + khi];
            f16x8 ha3 = *(const f16x8*)&h0r[lo16][96 + khi];
            REP8(INITX)
            REP8(PU0)
        }
        // write x_{t+1} into the idle buffer (loads have long since landed)
        {
            float* xd = &xbf[p ^ 1][xbrow][xcol0];
            ((float4*)xd)[0] = px0; ((float4*)xd)[1] = px1;
            ((float4*)xd)[2] = px2; ((float4*)xd)[3] = px3;
        }
        // ---- gates 0 (in-register) -> h0_t ----
        if (lane < 32) {
            G0R(0, 2, 4, 6, c0a, 0, 0) G0R(0, 2, 4, 6, c0a, 0, 1)
            G0R(0, 2, 4, 6, c0a, 0, 2) G0R(0, 2, 4, 6, c0a, 0, 3)
            G0R(1, 3, 5, 7, c0b, 1, 0) G0R(1, 3, 5, 7, c0b, 1, 1)
            G0R(1, 3, 5, 7, c0b, 1, 2) G0R(1, 3, 5, 7, c0b, 1, 3)
        }
        __syncthreads();   // h0_t + x_{t+1} staged + yst consumed

        // ---- phase C: aZ = b1 + W1^T h0_t + aU1 ----
        {
            f16x8 ha0 = *(const f16x8*)&h0c[lo16][khi];
            f16x8 ha1 = *(const f16x8*)&h0c[lo16][32 + khi];
            f16x8 ha2 = *(const f16x8*)&h0c[lo16][64 + khi];
            f16x8 ha3 = *(const f16x8*)&h0c[lo16][96 + khi];
            REP8(PW1)
        }
        // ---- gates 1 (in-register) -> h1_t, yst ----
        if (lane < 32) {
            G1R(0, 2, 4, 6, c1a, 0, 0) G1R(0, 2, 4, 6, c1a, 0, 1)
            G1R(0, 2, 4, 6, c1a, 0, 2) G1R(0, 2, 4, 6, c1a, 0, 3)
            G1R(1, 3, 5, 7, c1b, 1, 0) G1R(1, 3, 5, 7, c1b, 1, 1)
            G1R(1, 3, 5, 7, c1b, 1, 2) G1R(1, 3, 5, 7, c1b, 1, 3)
        }
        __syncthreads();   // h1_t + yst visible
    }
    // epilogue: flush y_{TT-1}
    {
        float4 yv = *(const float4*)&yst[xbrow][ycol];
        *(float4*)&y[((size_t)(B0 + xbrow) * TT + (TT - 1)) * HD + ycol] = yv;
    }
}

// ---------------- Prep: split y into f16 hi/lo, MFMA-fragment-packed ----------------
__global__ __launch_bounds__(256) void k_ysplit(
    const float* __restrict__ y, _Float16* __restrict__ yhi, _Float16* __restrict__ ylo)
{
    const int g = blockIdx.x * 256 + threadIdx.x;
    const int chunk = g >> 6;           // 0..1023
    const int lane = g & 63;
    const int mtile = chunk >> 2;
    const int kstep = chunk & 3;
    const int row = mtile * 16 + (lane & 15);
    const int kb = kstep * 32 + (lane >> 4) * 8;
    _Float16 hi[8], lo[8];
    #pragma unroll
    for (int j = 0; j < 8; ++j) {
        float v = y[(size_t)row * HD + kb + j];
        hi[j] = (_Float16)v;
        lo[j] = (_Float16)(v - (float)hi[j]);
    }
    *(float4*)&yhi[(size_t)chunk * 512 + lane * 8] = *(const float4*)hi;
    *(float4*)&ylo[(size_t)chunk * 512 + lane * 8] = *(const float4*)lo;
}

// ---------------- Kernel C (MFMA): out = y @ Wd + bd via f16 hi/lo split ----------------
__global__ __launch_bounds__(256) void k_dense_mfma(
    const _Float16* __restrict__ yhi, const _Float16* __restrict__ ylo,
    const _Float16* __restrict__ Whi, const _Float16* __restrict__ Wlo,
    const float* __restrict__ bd, float* __restrict__ out)
{
    const int tid = threadIdx.x;
    const int w = tid >> 6;
    const int lane = tid & 63;
    const int mtile = blockIdx.x * 4 + w;
    const int nt0 = blockIdx.y * 20;

    f16x8 Ah[4], Al[4];
    #pragma unroll
    for (int k = 0; k < 4; ++k) {
        Ah[k] = *(const f16x8*)&yhi[(size_t)(mtile * 4 + k) * 512 + lane * 8];
        Al[k] = *(const f16x8*)&ylo[(size_t)(mtile * 4 + k) * 512 + lane * 8];
    }

    const int m0 = mtile * 16;
    const int r0 = (lane >> 4) * 4;          // C/D row group (m89 mapping)

    for (int nt = 0; nt < 20; ++nt) {
        const int ntile = nt0 + nt;
        const size_t cbb = (size_t)ntile * 4 * 512 + lane * 8;
        f16x8 Bh[4], Bl[4];
        #pragma unroll
        for (int k = 0; k < 4; ++k) {
            Bh[k] = *(const f16x8*)&Whi[cbb + k * 512];
            Bl[k] = *(const f16x8*)&Wlo[cbb + k * 512];
        }
        f32x4 acc0 = {0.f, 0.f, 0.f, 0.f};
        f32x4 acc1 = {0.f, 0.f, 0.f, 0.f};
        #pragma unroll
        for (int k = 0; k < 4; ++k) {
            acc0 = __builtin_amdgcn_mfma_f32_16x16x32_f16(Ah[k], Bh[k], acc0, 0, 0, 0);
            acc1 = __builtin_amdgcn_mfma_f32_16x16x32_f16(Ah[k], Bl[k], acc1, 0, 0, 0);
            acc1 = __builtin_amdgcn_mfma_f32_16x16x32_f16(Al[k], Bh[k], acc1, 0, 0, 0);
        }
        const int col = ntile * 16 + (lane & 15);
        const float bias = bd[col];
        #pragma unroll
        for (int reg = 0; reg < 4; ++reg) {
            out[(size_t)(m0 + r0 + reg) * NV + col] = acc0[reg] + acc1[reg] + bias;
        }
    }
}

// ---------------- Kernel C (fallback, fp32 vector) ----------------
__global__ __launch_bounds__(256) void k_dense(
    const float* __restrict__ y, const float* __restrict__ Wd,
    const float* __restrict__ bd, float* __restrict__ out)
{
    __shared__ float ys[64 * HD];
    const int r0 = blockIdx.x * 64;
    const int v0 = blockIdx.y * 128;
    const int tid = threadIdx.x;
    for (int idx = tid; idx < 64 * HD; idx += 256) ys[idx] = y[(size_t)r0 * HD + idx];
    __syncthreads();
    const int tx = tid & 31;
    const int ty = tid >> 5;
    const int v = v0 + tx * 4;
    float4 bd4 = *(const float4*)&bd[v];
    float acc[8][4] = {};
    const float* yrow = &ys[(ty * 8) * HD];
    #pragma unroll 4
    for (int e = 0; e < HD; ++e) {
        float4 wv = *(const float4*)&Wd[(size_t)e * NV + v];
        #pragma unroll
        for (int j = 0; j < 8; ++j) {
            float yv = yrow[j * HD + e];
            acc[j][0] = fmaf(yv, wv.x, acc[j][0]);
            acc[j][1] = fmaf(yv, wv.y, acc[j][1]);
            acc[j][2] = fmaf(yv, wv.z, acc[j][2]);
            acc[j][3] = fmaf(yv, wv.w, acc[j][3]);
        }
    }
    #pragma unroll
    for (int j = 0; j < 8; ++j) {
        int rr = r0 + ty * 8 + j;
        float4 o4;
        o4.x = acc[j][0] + bd4.x;
        o4.y = acc[j][1] + bd4.y;
        o4.z = acc[j][2] + bd4.z;
        o4.w = acc[j][3] + bd4.w;
        *(float4*)&out[(size_t)rr * NV + v] = o4;
    }
}

extern "C" void kernel_launch(void* const* d_in, const int* in_sizes, int n_in,
                              void* d_out, int out_size, void* d_ws, size_t ws_size,
                              hipStream_t stream)
{
    const int*   inputs = (const int*)  d_in[0];
    const float* emb    = (const float*)d_in[1];
    const float* W0     = (const float*)d_in[2];
    const float* U0     = (const float*)d_in[3];
    const float* b0     = (const float*)d_in[4];
    const float* W1     = (const float*)d_in[5];
    const float* U1     = (const float*)d_in[6];
    const float* b1     = (const float*)d_in[7];
    const float* Wd     = (const float*)d_in[8];
    const float* bd     = (const float*)d_in[9];
    float* out = (float*)d_out;

    // ws layout (MFMA path): Z0x 8MB | yy 2MB | Whi 8MB | Wlo 8MB | yhi 1MB | ylo 1MB
    const size_t Z0X_B = (size_t)8 * 1024 * 1024;
    const size_t YY_B  = (size_t)2 * 1024 * 1024;
    const size_t WSP_B = (size_t)8000 * 512 * 2;        // 8,192,000
    const size_t YSP_B = (size_t)1024 * 512 * 2;        // 1,048,576
    const size_t NEED  = Z0X_B + YY_B + 2 * WSP_B + 2 * YSP_B + 4096;

    char* ws = (char*)d_ws;

    if (ws_size >= NEED) {
        float*     Z0x = (float*)ws;
        float*     yy  = (float*)(ws + Z0X_B);
        _Float16*  Whi = (_Float16*)(ws + Z0X_B + YY_B);
        _Float16*  Wlo = (_Float16*)(ws + Z0X_B + YY_B + WSP_B);
        _Float16*  yhi = (_Float16*)(ws + Z0X_B + YY_B + 2 * WSP_B);
        _Float16*  ylo = (_Float16*)(ws + Z0X_B + YY_B + 2 * WSP_B + YSP_B);

        k_prep<<<2512, 256, 0, stream>>>(inputs, emb, W0, b0, Z0x, Wd, Whi, Wlo);
        k_lstm_m3<<<4, 256, 0, stream>>>(Z0x, U0, W1, U1, b1, yy);
        k_ysplit<<<256, 256, 0, stream>>>(yy, yhi, ylo);
        k_dense_mfma<<<dim3(64, 100), 256, 0, stream>>>(yhi, ylo, Whi, Wlo, bd, out);
    } else {
        // small-ws fallback: Z0x in d_out tail, yy in ws, fp32 dense
        float* yy = (float*)ws;
        size_t out_bytes = (size_t)out_size * sizeof(float);
        float* Z0x = (float*)((char*)d_out + out_bytes - Z0X_B);

        k_prep<<<2512, 256, 0, stream>>>(inputs, emb, W0, b0, Z0x,
                                         Wd, nullptr, nullptr);
        k_lstm_m3<<<4, 256, 0, stream>>>(Z0x, U0, W1, U1, b1, yy);
        k_dense<<<dim3(64, 250), 256, 0, stream>>>(yy, Wd, bd, out);
    }
}

// Round 16
// 549.613 us; speedup vs baseline: 1.8450x; 1.8450x over previous
//
#include <hip/hip_runtime.h>
#include <math.h>

#define BB 32
#define TT 128
#define EE 128
#define HD 128
#define G4 512   // 4*H
#define NV 32000

typedef _Float16 f16x2  __attribute__((ext_vector_type(2)));
typedef _Float16 f16x4v __attribute__((ext_vector_type(4)));
typedef _Float16 f16x8  __attribute__((ext_vector_type(8)));
typedef float    f32x4  __attribute__((ext_vector_type(4)));

// ---------------- Kernel A: embed + W0 -> Z0x ----------------
__global__ __launch_bounds__(256) void k_embed(
    const int* __restrict__ inputs, const float* __restrict__ emb,
    const float* __restrict__ W0, const float* __restrict__ b0,
    float* __restrict__ Z0x)
{
    __shared__ float xs[8][EE];
    const int r0 = blockIdx.x * 8;
    const int tid = threadIdx.x;
    for (int i = tid; i < 8 * EE; i += 256) {
        int r = i >> 7, e = i & 127;
        int tok = inputs[r0 + r];
        xs[r][e] = emb[tok * EE + e];
    }
    __syncthreads();
    const int c2 = tid * 2;
    float2 bb2 = *(const float2*)&b0[c2];
    float acc[8][2];
    #pragma unroll
    for (int r = 0; r < 8; ++r) { acc[r][0] = bb2.x; acc[r][1] = bb2.y; }
    for (int e = 0; e < EE; ++e) {
        float2 w = *(const float2*)&W0[e * G4 + c2];
        #pragma unroll
        for (int r = 0; r < 8; ++r) {
            float x = xs[r][e];
            acc[r][0] = fmaf(x, w.x, acc[r][0]);
            acc[r][1] = fmaf(x, w.y, acc[r][1]);
        }
    }
    #pragma unroll
    for (int r = 0; r < 8; ++r) {
        float2 o2; o2.x = acc[r][0]; o2.y = acc[r][1];
        *(float2*)&Z0x[(size_t)(r0 + r) * G4 + c2] = o2;
    }
}

// ---------------- Kernel B: LSTM (blocks 0-3, R13-verbatim) + fused wsplit (blocks 4..2003) ----------------
// LSTM: 4 blocks x 256 thr, MFMA recurrence, zbuf LDS z-exchange, AGPR-pinned
// W1/U1 fragments, intrinsic MFMA (hazard-safe). 337 us proven (R13).
// wsplit blocks run concurrently on the ~252 idle CUs, hidden under the LSTM.
__device__ __forceinline__ float sigf(float x) {
    return __builtin_amdgcn_rcpf(1.f + __builtin_amdgcn_exp2f(x * -1.44269504088896f));
}
__device__ __forceinline__ float tanh_f(float x) {
    return 1.f - 2.f * __builtin_amdgcn_rcpf(1.f + __builtin_amdgcn_exp2f(x * 2.88539008177793f));
}
__device__ __forceinline__ f16x8 ldfrag(const float* __restrict__ M, int col, int k0) {
    f16x8 v;
    #pragma unroll
    for (int j = 0; j < 8; ++j) v[j] = (_Float16)M[(size_t)(k0 + j) * G4 + col];
    return v;
}

#define REP8(X) X(0) X(1) X(2) X(3) X(4) X(5) X(6) X(7)
#define MFMA(acc, a, b) acc = __builtin_amdgcn_mfma_f32_16x16x32_f16(a, b, acc, 0, 0, 0)

#define DECLF(n) f16x8 u0_##n##_0, u0_##n##_1, u0_##n##_2, u0_##n##_3, \
                       w1_##n##_0, w1_##n##_1, w1_##n##_2, w1_##n##_3, \
                       u1_##n##_0, u1_##n##_1, u1_##n##_2, u1_##n##_3;

#define LOADF(n) { const int cn = wc0 + (n) * 16 + lo16; \
    u0_##n##_0 = ldfrag(U0, cn, khi);      u0_##n##_1 = ldfrag(U0, cn, 32 + khi); \
    u0_##n##_2 = ldfrag(U0, cn, 64 + khi); u0_##n##_3 = ldfrag(U0, cn, 96 + khi); \
    w1_##n##_0 = ldfrag(W1, cn, khi);      w1_##n##_1 = ldfrag(W1, cn, 32 + khi); \
    w1_##n##_2 = ldfrag(W1, cn, 64 + khi); w1_##n##_3 = ldfrag(W1, cn, 96 + khi); \
    asm("" : "+a"(w1_##n##_0), "+a"(w1_##n##_1), "+a"(w1_##n##_2), "+a"(w1_##n##_3)); \
    u1_##n##_0 = ldfrag(U1, cn, khi);      u1_##n##_1 = ldfrag(U1, cn, 32 + khi); \
    u1_##n##_2 = ldfrag(U1, cn, 64 + khi); u1_##n##_3 = ldfrag(U1, cn, 96 + khi); \
    asm("" : "+a"(u1_##n##_0), "+a"(u1_##n##_1), "+a"(u1_##n##_2), "+a"(u1_##n##_3)); }

#define PA(n) { f32x4 acc = {0.f, 0.f, 0.f, 0.f}; \
    MFMA(acc, ha0, u0_##n##_0); MFMA(acc, ha1, u0_##n##_1); \
    MFMA(acc, ha2, u0_##n##_2); MFMA(acc, ha3, u0_##n##_3); \
    if (lane < 32) { const int cw = wc0 + (n) * 16 + lo16; const int br = (lane >> 4) * 4; \
        zbuf[br + 0][cw] = acc[0]; zbuf[br + 1][cw] = acc[1]; \
        zbuf[br + 2][cw] = acc[2]; zbuf[br + 3][cw] = acc[3]; } }

#define PC(n) { f32x4 acc = {0.f, 0.f, 0.f, 0.f}; \
    MFMA(acc, ha0, w1_##n##_0); MFMA(acc, ha1, w1_##n##_1); \
    MFMA(acc, ha2, w1_##n##_2); MFMA(acc, ha3, w1_##n##_3); \
    MFMA(acc, hb0, u1_##n##_0); MFMA(acc, hb1, u1_##n##_1); \
    MFMA(acc, hb2, u1_##n##_2); MFMA(acc, hb3, u1_##n##_3); \
    if (lane < 32) { const int cw = wc0 + (n) * 16 + lo16; const int br = (lane >> 4) * 4; \
        zbuf[br + 0][cw] = acc[0]; zbuf[br + 1][cw] = acc[1]; \
        zbuf[br + 2][cw] = acc[2]; zbuf[br + 3][cw] = acc[3]; } }

#define GT0(K, ZI, ZF, ZC, ZO) { \
    float ig = sigf(ZI), fg = sigf(ZF), og = sigf(ZO), gg = tanh_f(ZC); \
    float cn = fg * c0v[K] + ig * gg; c0v[K] = cn; hv[K] = (_Float16)(og * tanh_f(cn)); }

#define GT1(K, ZI, ZF, ZC, ZO, YO) { \
    float ig = sigf(ZI), fg = sigf(ZF), og = sigf(ZO), gg = tanh_f(ZC); \
    float cn = fg * c1v[K] + ig * gg; c1v[K] = cn; float hn = og * tanh_f(cn); \
    hv[K] = (_Float16)hn; YO = hn; }

__global__ __launch_bounds__(256, 1) void k_lstm_mw(
    const float* __restrict__ Z0x,
    const float* __restrict__ U0, const float* __restrict__ W1,
    const float* __restrict__ U1, const float* __restrict__ b1,
    float* __restrict__ y,
    const float* __restrict__ Wd, _Float16* __restrict__ Whi, _Float16* __restrict__ Wlo)
{
    const int tid  = threadIdx.x;

    if (blockIdx.x >= 4) {
        // ---- fused Wd hi/lo split (independent work on idle CUs) ----
        if (Whi == nullptr) return;
        const int g = (blockIdx.x - 4) * 256 + tid;
        const int chunk = g >> 6;           // 0..7999
        const int ln = g & 63;
        const int ntile = chunk >> 2;
        const int kstep = chunk & 3;
        const int n = ntile * 16 + (ln & 15);
        const int kb = kstep * 32 + (ln >> 4) * 8;
        _Float16 hi[8], lo[8];
        #pragma unroll
        for (int j = 0; j < 8; ++j) {
            float v = Wd[(size_t)(kb + j) * NV + n];
            hi[j] = (_Float16)v;
            lo[j] = (_Float16)(v - (float)hi[j]);
        }
        *(float4*)&Whi[(size_t)chunk * 512 + ln * 8] = *(const float4*)hi;
        *(float4*)&Wlo[(size_t)chunk * 512 + ln * 8] = *(const float4*)lo;
        return;
    }

    const int lane = tid & 63;
    const int wc0  = (tid >> 6) * 128;     // wave's column base
    const int lo16 = lane & 15;
    const int khi  = (lane >> 4) * 8;
    const int B0   = blockIdx.x * 8;       // batch base

    __shared__ float     zbuf[8][516];     // z scores, +4 pad
    __shared__ _Float16  h0p[16][136];     // h0, rows 8-15 stay zero, +8 pad
    __shared__ _Float16  h1p[16][136];

    REP8(DECLF)
    REP8(LOADF)

    // gate-thread mapping: bq = batch, 4 h-units per thread
    const int bq  = tid >> 5;              // 0..7
    const int h0i = (tid & 31) * 4;        // 0..124
    const float* zx_base = Z0x + ((size_t)(B0 + bq) * TT) * G4;
    float*       y_base  = y   + ((size_t)(B0 + bq) * TT) * HD + h0i;

    const float4 b1_i = *(const float4*)&b1[0 * 128 + h0i];
    const float4 b1_f = *(const float4*)&b1[1 * 128 + h0i];
    const float4 b1_c = *(const float4*)&b1[2 * 128 + h0i];
    const float4 b1_o = *(const float4*)&b1[3 * 128 + h0i];

    for (int i = tid; i < 16 * 136; i += 256) {
        ((_Float16*)h0p)[i] = (_Float16)0.f;
        ((_Float16*)h1p)[i] = (_Float16)0.f;
    }
    f32x4 c0v = {0.f, 0.f, 0.f, 0.f};
    f32x4 c1v = {0.f, 0.f, 0.f, 0.f};
    __syncthreads();

    for (int t = 0; t < TT; ++t) {
        // prefetch Z0x gate rows (consumed in gates-0, hidden under MFMA)
        const float* zx = zx_base + (size_t)t * G4;
        const float4 x_i = *(const float4*)&zx[0 * 128 + h0i];
        const float4 x_f = *(const float4*)&zx[1 * 128 + h0i];
        const float4 x_c = *(const float4*)&zx[2 * 128 + h0i];
        const float4 x_o = *(const float4*)&zx[3 * 128 + h0i];

        // ---- phase A: zbuf = U0^T h0_{t-1} ----
        {
            f16x8 ha0 = *(const f16x8*)&h0p[lo16][khi];
            f16x8 ha1 = *(const f16x8*)&h0p[lo16][32 + khi];
            f16x8 ha2 = *(const f16x8*)&h0p[lo16][64 + khi];
            f16x8 ha3 = *(const f16x8*)&h0p[lo16][96 + khi];
            REP8(PA)
        }
        __syncthreads();

        // ---- phase B: layer-0 gates -> h0_t ----
        {
            const float4 zi4 = *(const float4*)&zbuf[bq][0 * 128 + h0i];
            const float4 zf4 = *(const float4*)&zbuf[bq][1 * 128 + h0i];
            const float4 zc4 = *(const float4*)&zbuf[bq][2 * 128 + h0i];
            const float4 zo4 = *(const float4*)&zbuf[bq][3 * 128 + h0i];
            f16x4v hv;
            GT0(0, zi4.x + x_i.x, zf4.x + x_f.x, zc4.x + x_c.x, zo4.x + x_o.x)
            GT0(1, zi4.y + x_i.y, zf4.y + x_f.y, zc4.y + x_c.y, zo4.y + x_o.y)
            GT0(2, zi4.z + x_i.z, zf4.z + x_f.z, zc4.z + x_c.z, zo4.z + x_o.z)
            GT0(3, zi4.w + x_i.w, zf4.w + x_f.w, zc4.w + x_c.w, zo4.w + x_o.w)
            *(f16x4v*)&h0p[bq][h0i] = hv;
        }
        __syncthreads();

        // ---- phase C: zbuf = W1^T h0_t + U1^T h1_{t-1} ----
        {
            f16x8 ha0 = *(const f16x8*)&h0p[lo16][khi];
            f16x8 ha1 = *(const f16x8*)&h0p[lo16][32 + khi];
            f16x8 ha2 = *(const f16x8*)&h0p[lo16][64 + khi];
            f16x8 ha3 = *(const f16x8*)&h0p[lo16][96 + khi];
            f16x8 hb0 = *(const f16x8*)&h1p[lo16][khi];
            f16x8 hb1 = *(const f16x8*)&h1p[lo16][32 + khi];
            f16x8 hb2 = *(const f16x8*)&h1p[lo16][64 + khi];
            f16x8 hb3 = *(const f16x8*)&h1p[lo16][96 + khi];
            REP8(PC)
        }
        __syncthreads();

        // ---- phase D: layer-1 gates -> h1_t, y ----
        {
            const float4 zi4 = *(const float4*)&zbuf[bq][0 * 128 + h0i];
            const float4 zf4 = *(const float4*)&zbuf[bq][1 * 128 + h0i];
            const float4 zc4 = *(const float4*)&zbuf[bq][2 * 128 + h0i];
            const float4 zo4 = *(const float4*)&zbuf[bq][3 * 128 + h0i];
            f16x4v hv; float4 yv;
            GT1(0, zi4.x + b1_i.x, zf4.x + b1_f.x, zc4.x + b1_c.x, zo4.x + b1_o.x, yv.x)
            GT1(1, zi4.y + b1_i.y, zf4.y + b1_f.y, zc4.y + b1_c.y, zo4.y + b1_o.y, yv.y)
            GT1(2, zi4.z + b1_i.z, zf4.z + b1_f.z, zc4.z + b1_c.z, zo4.z + b1_o.z, yv.z)
            GT1(3, zi4.w + b1_i.w, zf4.w + b1_f.w, zc4.w + b1_c.w, zo4.w + b1_o.w, yv.w)
            *(f16x4v*)&h1p[bq][h0i] = hv;
            *(float4*)(y_base + (size_t)t * HD) = yv;
        }
        __syncthreads();
    }
}

// ---------------- Prep: split y into f16 hi/lo, MFMA-fragment-packed ----------------
__global__ __launch_bounds__(256) void k_ysplit(
    const float* __restrict__ y, _Float16* __restrict__ yhi, _Float16* __restrict__ ylo)
{
    const int g = blockIdx.x * 256 + threadIdx.x;
    const int chunk = g >> 6;           // 0..1023
    const int lane = g & 63;
    const int mtile = chunk >> 2;
    const int kstep = chunk & 3;
    const int row = mtile * 16 + (lane & 15);
    const int kb = kstep * 32 + (lane >> 4) * 8;
    _Float16 hi[8], lo[8];
    #pragma unroll
    for (int j = 0; j < 8; ++j) {
        float v = y[(size_t)row * HD + kb + j];
        hi[j] = (_Float16)v;
        lo[j] = (_Float16)(v - (float)hi[j]);
    }
    *(float4*)&yhi[(size_t)chunk * 512 + lane * 8] = *(const float4*)hi;
    *(float4*)&ylo[(size_t)chunk * 512 + lane * 8] = *(const float4*)lo;
}

// ---------------- Kernel C (MFMA, B-resident): out = y @ Wd + bd ----------------
// Wave holds 4 ntiles' B fragments in registers (128 VGPR) and loops over 32
// mtiles, streaming A. B traffic drops 1 GB -> 128 MB. grid (8, 125).
__global__ __launch_bounds__(256) void k_dense_mfma2(
    const _Float16* __restrict__ yhi, const _Float16* __restrict__ ylo,
    const _Float16* __restrict__ Whi, const _Float16* __restrict__ Wlo,
    const float* __restrict__ bd, float* __restrict__ out)
{
    const int tid  = threadIdx.x;
    const int w    = tid >> 6;
    const int lane = tid & 63;
    const int nt0  = blockIdx.y * 16 + w * 4;    // wave's 4 ntiles
    const int mt0  = blockIdx.x * 32;            // 32 mtiles per block

    f16x8 Bh[4][4], Bl[4][4];
    #pragma unroll
    for (int n = 0; n < 4; ++n) {
        const size_t cb = (size_t)(nt0 + n) * 4 * 512 + lane * 8;
        #pragma unroll
        for (int k = 0; k < 4; ++k) {
            Bh[n][k] = *(const f16x8*)&Whi[cb + k * 512];
            Bl[n][k] = *(const f16x8*)&Wlo[cb + k * 512];
        }
    }
    float bias[4];
    #pragma unroll
    for (int n = 0; n < 4; ++n) bias[n] = bd[(nt0 + n) * 16 + (lane & 15)];

    const int r0 = (lane >> 4) * 4;              // C/D row group (m89 mapping)

    for (int mt = 0; mt < 32; ++mt) {
        const int mtile = mt0 + mt;
        const size_t ab = (size_t)mtile * 4 * 512 + lane * 8;

        f32x4 acc0[4] = {{0,0,0,0},{0,0,0,0},{0,0,0,0},{0,0,0,0}};
        f32x4 acc1[4] = {{0,0,0,0},{0,0,0,0},{0,0,0,0},{0,0,0,0}};

        {   // A-hi pass: acc0 += Ah*Bh ; acc1 += Ah*Bl
            f16x8 A0 = *(const f16x8*)&yhi[ab];
            f16x8 A1 = *(const f16x8*)&yhi[ab + 512];
            f16x8 A2 = *(const f16x8*)&yhi[ab + 1024];
            f16x8 A3 = *(const f16x8*)&yhi[ab + 1536];
            #pragma unroll
            for (int n = 0; n < 4; ++n) {
                acc0[n] = __builtin_amdgcn_mfma_f32_16x16x32_f16(A0, Bh[n][0], acc0[n], 0, 0, 0);
                acc0[n] = __builtin_amdgcn_mfma_f32_16x16x32_f16(A1, Bh[n][1], acc0[n], 0, 0, 0);
                acc0[n] = __builtin_amdgcn_mfma_f32_16x16x32_f16(A2, Bh[n][2], acc0[n], 0, 0, 0);
                acc0[n] = __builtin_amdgcn_mfma_f32_16x16x32_f16(A3, Bh[n][3], acc0[n], 0, 0, 0);
                acc1[n] = __builtin_amdgcn_mfma_f32_16x16x32_f16(A0, Bl[n][0], acc1[n], 0, 0, 0);
                acc1[n] = __builtin_amdgcn_mfma_f32_16x16x32_f16(A1, Bl[n][1], acc1[n], 0, 0, 0);
                acc1[n] = __builtin_amdgcn_mfma_f32_16x16x32_f16(A2, Bl[n][2], acc1[n], 0, 0, 0);
                acc1[n] = __builtin_amdgcn_mfma_f32_16x16x32_f16(A3, Bl[n][3], acc1[n], 0, 0, 0);
            }
        }
        {   // A-lo pass: acc1 += Al*Bh
            f16x8 A0 = *(const f16x8*)&ylo[ab];
            f16x8 A1 = *(const f16x8*)&ylo[ab + 512];
            f16x8 A2 = *(const f16x8*)&ylo[ab + 1024];
            f16x8 A3 = *(const f16x8*)&ylo[ab + 1536];
            #pragma unroll
            for (int n = 0; n < 4; ++n) {
                acc1[n] = __builtin_amdgcn_mfma_f32_16x16x32_f16(A0, Bh[n][0], acc1[n], 0, 0, 0);
                acc1[n] = __builtin_amdgcn_mfma_f32_16x16x32_f16(A1, Bh[n][1], acc1[n], 0, 0, 0);
                acc1[n] = __builtin_amdgcn_mfma_f32_16x16x32_f16(A2, Bh[n][2], acc1[n], 0, 0, 0);
                acc1[n] = __builtin_amdgcn_mfma_f32_16x16x32_f16(A3, Bh[n][3], acc1[n], 0, 0, 0);
            }
        }
        const int m0 = mtile * 16;
        #pragma unroll
        for (int n = 0; n < 4; ++n) {
            const int col = (nt0 + n) * 16 + (lane & 15);
            #pragma unroll
            for (int reg = 0; reg < 4; ++reg) {
                out[(size_t)(m0 + r0 + reg) * NV + col] = acc0[n][reg] + acc1[n][reg] + bias[n];
            }
        }
    }
}

// ---------------- Kernel C (fallback, fp32 vector) ----------------
__global__ __launch_bounds__(256) void k_dense(
    const float* __restrict__ y, const float* __restrict__ Wd,
    const float* __restrict__ bd, float* __restrict__ out)
{
    __shared__ float ys[64 * HD];
    const int r0 = blockIdx.x * 64;
    const int v0 = blockIdx.y * 128;
    const int tid = threadIdx.x;
    for (int idx = tid; idx < 64 * HD; idx += 256) ys[idx] = y[(size_t)r0 * HD + idx];
    __syncthreads();
    const int tx = tid & 31;
    const int ty = tid >> 5;
    const int v = v0 + tx * 4;
    float4 bd4 = *(const float4*)&bd[v];
    float acc[8][4] = {};
    const float* yrow = &ys[(ty * 8) * HD];
    #pragma unroll 4
    for (int e = 0; e < HD; ++e) {
        float4 wv = *(const float4*)&Wd[(size_t)e * NV + v];
        #pragma unroll
        for (int j = 0; j < 8; ++j) {
            float yv = yrow[j * HD + e];
            acc[j][0] = fmaf(yv, wv.x, acc[j][0]);
            acc[j][1] = fmaf(yv, wv.y, acc[j][1]);
            acc[j][2] = fmaf(yv, wv.z, acc[j][2]);
            acc[j][3] = fmaf(yv, wv.w, acc[j][3]);
        }
    }
    #pragma unroll
    for (int j = 0; j < 8; ++j) {
        int rr = r0 + ty * 8 + j;
        float4 o4;
        o4.x = acc[j][0] + bd4.x;
        o4.y = acc[j][1] + bd4.y;
        o4.z = acc[j][2] + bd4.z;
        o4.w = acc[j][3] + bd4.w;
        *(float4*)&out[(size_t)rr * NV + v] = o4;
    }
}

extern "C" void kernel_launch(void* const* d_in, const int* in_sizes, int n_in,
                              void* d_out, int out_size, void* d_ws, size_t ws_size,
                              hipStream_t stream)
{
    const int*   inputs = (const int*)  d_in[0];
    const float* emb    = (const float*)d_in[1];
    const float* W0     = (const float*)d_in[2];
    const float* U0     = (const float*)d_in[3];
    const float* b0     = (const float*)d_in[4];
    const float* W1     = (const float*)d_in[5];
    const float* U1     = (const float*)d_in[6];
    const float* b1     = (const float*)d_in[7];
    const float* Wd     = (const float*)d_in[8];
    const float* bd     = (const float*)d_in[9];
    float* out = (float*)d_out;

    // ws layout (MFMA path): Z0x 8MB | yy 2MB | Whi 8MB | Wlo 8MB | yhi 1MB | ylo 1MB
    const size_t Z0X_B = (size_t)8 * 1024 * 1024;
    const size_t YY_B  = (size_t)2 * 1024 * 1024;
    const size_t WSP_B = (size_t)8000 * 512 * 2;        // 8,192,000
    const size_t YSP_B = (size_t)1024 * 512 * 2;        // 1,048,576
    const size_t NEED  = Z0X_B + YY_B + 2 * WSP_B + 2 * YSP_B + 4096;

    char* ws = (char*)d_ws;

    if (ws_size >= NEED) {
        float*     Z0x = (float*)ws;
        float*     yy  = (float*)(ws + Z0X_B);
        _Float16*  Whi = (_Float16*)(ws + Z0X_B + YY_B);
        _Float16*  Wlo = (_Float16*)(ws + Z0X_B + YY_B + WSP_B);
        _Float16*  yhi = (_Float16*)(ws + Z0X_B + YY_B + 2 * WSP_B);
        _Float16*  ylo = (_Float16*)(ws + Z0X_B + YY_B + 2 * WSP_B + YSP_B);

        k_embed<<<512, 256, 0, stream>>>(inputs, emb, W0, b0, Z0x);
        k_lstm_mw<<<2004, 256, 0, stream>>>(Z0x, U0, W1, U1, b1, yy, Wd, Whi, Wlo);
        k_ysplit<<<256, 256, 0, stream>>>(yy, yhi, ylo);
        k_dense_mfma2<<<dim3(8, 125), 256, 0, stream>>>(yhi, ylo, Whi, Wlo, bd, out);
    } else {
        // small-ws fallback: Z0x in d_out tail, yy in ws, fp32 dense
        float* yy = (float*)ws;
        size_t out_bytes = (size_t)out_size * sizeof(float);
        float* Z0x = (float*)((char*)d_out + out_bytes - Z0X_B);

        k_embed<<<512, 256, 0, stream>>>(inputs, emb, W0, b0, Z0x);
        k_lstm_mw<<<2004, 256, 0, stream>>>(Z0x, U0, W1, U1, b1, yy,
                                            Wd, nullptr, nullptr);
        k_dense<<<dim3(64, 250), 256, 0, stream>>>(yy, Wd, bd, out);
    }
}